// Round 9
// baseline (531.083 us; speedup 1.0000x reference)
//
#include <hip/hip_runtime.h>
#include <hip/hip_bf16.h>

#define NN 50000
#define NE 800000

typedef __attribute__((ext_vector_type(8))) short s16x8;
typedef __attribute__((ext_vector_type(4))) float f32x4;
typedef __attribute__((ext_vector_type(2))) float f32x2;

__device__ __forceinline__ float bf2f(unsigned short u) {
  union { unsigned int i; float f; } v; v.i = ((unsigned int)u) << 16; return v.f;
}
__device__ __forceinline__ unsigned short f2bf(float f) {
  union { unsigned int i; float f; } v; v.f = f;
  unsigned int x = v.i;
  return (unsigned short)((x + 0x7FFFu + ((x >> 16) & 1u)) >> 16);
}

// ---- dtype probe ----
__global__ void k_detect(const unsigned short* __restrict__ xh, int* __restrict__ flag) {
  int t = threadIdx.x;
  float b0 = bf2f(xh[2 * t]);
  float b1 = bf2f(xh[2 * t + 1]);
  bool ok = (b0 == b0) && (b1 == b1) && fabsf(b0) < 64.f && fabsf(b1) < 64.f;
  unsigned long long m = __ballot(ok);
  if (t == 0) *flag = (m == ~0ull) ? 1 : 0;
}

// ---- x -> bf16 buffer (only needed when input is fp32) ----
__global__ void k_cvt_x(const void* __restrict__ src, unsigned short* __restrict__ dst, int n,
                        const int* __restrict__ flag) {
  if (*flag) return;  // bf16 input: GEMM reads d_in[0] directly
  int i = blockIdx.x * 256 + threadIdx.x;
  if (i >= n) return;
  dst[i] = f2bf(((const float*)src)[i]);
}

struct SmallPack { const void* src[20]; int off[21]; };

__global__ void k_cvt_small(SmallPack pk, float* __restrict__ dst, int total,
                            const int* __restrict__ flag) {
  int i = blockIdx.x * 256 + threadIdx.x;
  if (i >= total) return;
  int d = 0;
  while (i >= pk.off[d + 1]) d++;
  int local = i - pk.off[d];
  if (*flag) dst[i] = bf2f(((const unsigned short*)pk.src[d])[local]);
  else       dst[i] = ((const float*)pk.src[d])[local];
}

// ---- W -> W^T bf16 ----
struct WPack { const void* w[5]; };

__global__ void k_prep_w(WPack wp, unsigned short* __restrict__ wt, const int* __restrict__ flag) {
  const int KN[5]   = {32768, 32768, 16384, 8192, 256};
  const int LGN[5]  = {8, 7, 7, 6, 2};
  const int KK[5]   = {128, 256, 128, 128, 64};
  const int OFF[5]  = {0, 32768, 65536, 81920, 90112};
  int l = blockIdx.y;
  int i = blockIdx.x * 256 + threadIdx.x;
  if (i >= KN[l]) return;
  int k = i >> LGN[l];
  int n = i & ((1 << LGN[l]) - 1);
  unsigned short v;
  if (*flag) v = ((const unsigned short*)wp.w[l])[i];
  else       v = f2bf(((const float*)wp.w[l])[i]);
  wt[OFF[l] + n * KK[l] + k] = v;
}

// ---- CSR build ----
__global__ void k_count(const int* __restrict__ dst, int* __restrict__ fill) {
  int e = blockIdx.x * 256 + threadIdx.x;
  if (e < NE) atomicAdd(&fill[dst[e]], 1);
}

__global__ void k_scan1(const int* __restrict__ deg, int* __restrict__ outp, int* __restrict__ csum) {
  __shared__ int s[256];
  int t = threadIdx.x, i = blockIdx.x * 256 + t;
  int v = (i < NN) ? deg[i] : 0;
  s[t] = v; __syncthreads();
  for (int o = 1; o < 256; o <<= 1) {
    int x = (t >= o) ? s[t - o] : 0; __syncthreads();
    s[t] += x; __syncthreads();
  }
  if (i < NN) outp[i] = s[t] - v;
  if (t == 255) csum[blockIdx.x] = s[255];
}

__global__ void k_scan2(int* __restrict__ csum, int nc) {
  __shared__ int s[256];
  int t = threadIdx.x;
  int v = (t < nc) ? csum[t] : 0;
  s[t] = v; __syncthreads();
  for (int o = 1; o < 256; o <<= 1) {
    int x = (t >= o) ? s[t - o] : 0; __syncthreads();
    s[t] += x; __syncthreads();
  }
  if (t < nc) csum[t] = s[t] - v;
}

__global__ void k_scan3(int* __restrict__ indptr, const int* __restrict__ csum, int* __restrict__ fill) {
  int i = blockIdx.x * 256 + threadIdx.x;
  if (i < NN) { int v = indptr[i] + csum[blockIdx.x]; indptr[i] = v; fill[i] = v; }
  if (i == NN) indptr[NN] = NE;
}

__global__ void k_fill(const int* __restrict__ src, const int* __restrict__ dst,
                       int* __restrict__ fill, int* __restrict__ csr) {
  int e = blockIdx.x * 256 + threadIdx.x;
  if (e < NE) { int p = atomicAdd(&fill[dst[e]], 1); csr[p] = src[e]; }
}

// ---- bf16 MFMA GEMM, no LDS: A frags direct from global, fused el/er ----
// A selected by *flag between raw input (bf16 pass-through) and converted buffer.
__global__ __launch_bounds__(256) void k_gemm_mfma(const void* __restrict__ Araw,
                                                   const unsigned short* __restrict__ Acvt,
                                                   const unsigned short* __restrict__ Wt,
                                                   unsigned short* __restrict__ Zh,
                                                   const float* __restrict__ al,
                                                   const float* __restrict__ ar,
                                                   float* __restrict__ el, float* __restrict__ er,
                                                   int M, int K, int Nc, int H,
                                                   const int* __restrict__ flag) {
  const unsigned short* A = (*flag) ? (const unsigned short*)Araw : Acvt;
  int tid = threadIdx.x;
  int w = tid >> 6, l = tid & 63;
  int l15 = l & 15, l16 = l >> 4;
  int row0 = blockIdx.y * 64, col0 = blockIdx.x * 64;
  int h = blockIdx.x;
  int arow = row0 + w * 16 + l15;
  if (arow >= M) arow = M - 1;  // clamp; OOB output rows are store-guarded
  const unsigned short* aptr = A + (size_t)arow * K + l16 * 8;
  f32x4 acc[4] = {};
#pragma unroll 4
  for (int k0 = 0; k0 < K; k0 += 32) {
    s16x8 afrag = *(const s16x8*)(aptr + k0);
#pragma unroll
    for (int nt = 0; nt < 4; nt++) {
      s16x8 bfrag = *(const s16x8*)&Wt[(size_t)(col0 + nt * 16 + l15) * K + k0 + l16 * 8];
      acc[nt] = __builtin_amdgcn_mfma_f32_16x16x32_bf16(afrag, bfrag, acc[nt], 0, 0, 0);
    }
  }
  // epilogue: Zh store + fused el/er
  float alv[4], arv[4];
#pragma unroll
  for (int nt = 0; nt < 4; nt++) {
    alv[nt] = al[h * 64 + nt * 16 + l15];
    arv[nt] = ar[h * 64 + nt * 16 + l15];
  }
#pragma unroll
  for (int r = 0; r < 4; r++) {
    int grow = row0 + w * 16 + l16 * 4 + r;
    bool ok = grow < M;
    float vl = 0.f, vr = 0.f;
#pragma unroll
    for (int nt = 0; nt < 4; nt++) {
      float a = acc[nt][r];
      if (ok) Zh[(size_t)grow * Nc + col0 + nt * 16 + l15] = f2bf(a);
      vl += a * alv[nt];
      vr += a * arv[nt];
    }
#pragma unroll
    for (int o = 1; o < 16; o <<= 1) {
      vl += __shfl_xor(vl, o, 64);
      vr += __shfl_xor(vr, o, 64);
    }
    if (l15 == 0 && ok) {
      el[grow * H + h] = vl;
      er[grow * H + h] = vr;
    }
  }
}

// ---- fused softmax + aggregation: wave per dst, packed-f32 accumulate ----
template <int HF, int H>
__global__ void k_agg_f(const int* __restrict__ indptr, const int* __restrict__ csr,
                        const float* __restrict__ el, const float* __restrict__ er,
                        const unsigned short* __restrict__ Zh, const float* __restrict__ bias,
                        unsigned short* __restrict__ outp) {
  const int LPE = HF / 8;   // lanes per edge
  const int EPI = 64 / LPE; // edges in flight
  int g = blockIdx.x * 256 + threadIdx.x;
  int n = g >> 6, lane = g & 63;
  if (n >= NN) return;
  int grp = lane / LPE;
  int fl = lane % LPE;
  int f0 = fl * 8;
  int h = f0 >> 6;
  int p0 = indptr[n], p1 = indptr[n + 1];
  float erv = er[n * H + h];
  float s = 0.f;
  f32x2 acc2[4] = {};
#define AGG_BODY(P)                                                          \
  {                                                                          \
    int si_ = csr[P];                                                        \
    float e_ = el[si_ * H + h] + erv;                                        \
    e_ = (e_ > 0.f) ? e_ : 0.2f * e_;                                        \
    float x_ = __expf(fminf(e_, 80.f));                                      \
    s += x_;                                                                 \
    f32x2 xv_ = {x_, x_};                                                    \
    uint4 v_ = *(const uint4*)(Zh + (size_t)si_ * HF + f0);                  \
    unsigned int w_[4] = {v_.x, v_.y, v_.z, v_.w};                           \
    _Pragma("unroll") for (int q = 0; q < 4; q++) {                          \
      union { unsigned int u; float f; } lo_, hi_;                           \
      lo_.u = w_[q] << 16; hi_.u = w_[q] & 0xffff0000u;                      \
      f32x2 z_ = {lo_.f, hi_.f};                                             \
      acc2[q] += xv_ * z_;                                                   \
    }                                                                        \
  }
  int p = p0 + grp;
  for (; p + 3 * EPI < p1; p += 4 * EPI) {
    AGG_BODY(p); AGG_BODY(p + EPI); AGG_BODY(p + 2 * EPI); AGG_BODY(p + 3 * EPI);
  }
  for (; p < p1; p += EPI) AGG_BODY(p);
#undef AGG_BODY
#pragma unroll
  for (int o = LPE; o < 64; o <<= 1) {
    s += __shfl_xor(s, o, 64);
#pragma unroll
    for (int q = 0; q < 4; q++) {
      acc2[q].x += __shfl_xor(acc2[q].x, o, 64);
      acc2[q].y += __shfl_xor(acc2[q].y, o, 64);
    }
  }
  if (grp == 0) {
    float inv = (p1 > p0) ? 1.f / s : 0.f;
    unsigned int pk[4];
#pragma unroll
    for (int q = 0; q < 4; q++) {
      float x0 = acc2[q].x * inv + bias[f0 + 2 * q];
      float x1 = acc2[q].y * inv + bias[f0 + 2 * q + 1];
      x0 = (x0 > 0.f) ? x0 : expm1f(x0);
      x1 = (x1 > 0.f) ? x1 : expm1f(x1);
      pk[q] = (unsigned int)f2bf(x0) | ((unsigned int)f2bf(x1) << 16);
    }
    *(uint4*)&outp[(size_t)n * HF + f0] = make_uint4(pk[0], pk[1], pk[2], pk[3]);
  }
}

// ---- layer 5 linear (64 -> 4) + scores ----
__global__ void k_l5(const unsigned short* __restrict__ hb, const float* __restrict__ W5,
                     const float* __restrict__ al5, const float* __restrict__ ar5,
                     float* __restrict__ z5, float* __restrict__ el, float* __restrict__ er) {
  __shared__ float W5s[256];
  int t = threadIdx.x;
  W5s[t] = W5[t];
  __syncthreads();
  int n = blockIdx.x * 256 + t;
  if (n >= NN) return;
  float z[4] = {};
#pragma unroll
  for (int kq = 0; kq < 8; kq++) {
    uint4 v = *(const uint4*)&hb[(size_t)n * 64 + kq * 8];
    unsigned int w_[4] = {v.x, v.y, v.z, v.w};
#pragma unroll
    for (int q = 0; q < 4; q++) {
      union { unsigned int u; float f; } lo, hi;
      lo.u = w_[q] << 16; hi.u = w_[q] & 0xffff0000u;
      int k = kq * 8 + 2 * q;
#pragma unroll
      for (int c = 0; c < 4; c++) z[c] += lo.f * W5s[k * 4 + c] + hi.f * W5s[(k + 1) * 4 + c];
    }
  }
  el[n] = z[0] * al5[0] + z[1] * al5[1] + z[2] * al5[2] + z[3] * al5[3];
  er[n] = z[0] * ar5[0] + z[1] * ar5[1] + z[2] * ar5[2] + z[3] * ar5[3];
  *(float4*)&z5[n * 4] = make_float4(z[0], z[1], z[2], z[3]);
}

// ---- final fused softmax+agg (H=1,F=4), thread per dst ----
__global__ void k_agg4_f(const int* __restrict__ indptr, const int* __restrict__ csr,
                         const float* __restrict__ el, const float* __restrict__ er,
                         const float* __restrict__ Z, const float* __restrict__ bias,
                         void* __restrict__ outp, const int* __restrict__ flag) {
  int n = blockIdx.x * 256 + threadIdx.x;
  if (n >= NN) return;
  int p0 = indptr[n], p1 = indptr[n + 1];
  float erv = er[n];
  float s = 0.f;
  float ax = 0.f, ay = 0.f, az = 0.f, aw = 0.f;
  for (int p = p0; p < p1; p++) {
    int si = csr[p];
    float e = el[si] + erv;
    e = (e > 0.f) ? e : 0.2f * e;
    float x = __expf(fminf(e, 80.f));
    s += x;
    float4 z = *(const float4*)&Z[si * 4];
    ax += x * z.x; ay += x * z.y; az += x * z.z; aw += x * z.w;
  }
  float inv = (p1 > p0) ? 1.f / s : 0.f;
  ax = ax * inv + bias[0]; ay = ay * inv + bias[1];
  az = az * inv + bias[2]; aw = aw * inv + bias[3];
  if (*flag) {
    unsigned short* o = (unsigned short*)outp;
    o[n * 4 + 0] = f2bf(ax); o[n * 4 + 1] = f2bf(ay);
    o[n * 4 + 2] = f2bf(az); o[n * 4 + 3] = f2bf(aw);
  } else {
    float* o = (float*)outp;
    o[n * 4 + 0] = ax; o[n * 4 + 1] = ay; o[n * 4 + 2] = az; o[n * 4 + 3] = aw;
  }
}

extern "C" void kernel_launch(void* const* d_in, const int* in_sizes, int n_in,
                              void* d_out, int out_size, void* d_ws, size_t ws_size,
                              hipStream_t stream) {
  (void)in_sizes; (void)n_in; (void)out_size; (void)ws_size;
  static const int fin[5] = {128, 256, 128, 128, 64};
  static const int Hh[5]  = {4, 2, 2, 1, 1};
  static const int HF[5]  = {256, 128, 128, 64, 4};
  static const int WtOff[5] = {0, 32768, 65536, 81920, 90112};

  char* ws = (char*)d_ws;
  size_t cur = 0;
  auto alloc = [&](size_t b) -> void* { void* p = ws + cur; cur += (b + 255) & ~(size_t)255; return p; };

  int*   flag   = (int*)alloc(4);
  int*   csum   = (int*)alloc(1024);
  int*   indptr = (int*)alloc((NN + 1) * 4);
  int*   fill   = (int*)alloc((size_t)NN * 4);
  int*   csr    = (int*)alloc((size_t)NE * 4);
  float* el     = (float*)alloc((size_t)NN * 4 * 4);
  float* er     = (float*)alloc((size_t)NN * 4 * 4);
  float* smallf = (float*)alloc(100000 * 4);
  unsigned short* xh   = (unsigned short*)alloc((size_t)NN * 128 * 2);
  unsigned short* wt   = (unsigned short*)alloc(90368 * 2);
  unsigned short* hb0  = (unsigned short*)alloc((size_t)NN * 256 * 2);
  unsigned short* hb1  = (unsigned short*)alloc((size_t)NN * 256 * 2);
  unsigned short* zh   = (unsigned short*)alloc((size_t)NN * 256 * 2);
  float* z5     = (float*)alloc((size_t)NN * 4 * 4);

  const int* srcIdx = (const int*)d_in[1];
  const int* dstIdx = (const int*)d_in[2];

  SmallPack pk;
  WPack wpk;
  int off = 0;
  int aloff[5], aroff[5], boff[5], w5off = 0;
  for (int i = 0; i < 5; i++) {
    pk.src[i * 4 + 0] = d_in[3 + i * 4 + 0]; pk.off[i * 4 + 0] = off;
    wpk.w[i] = d_in[3 + i * 4 + 0];
    if (i == 4) w5off = off;
    off += fin[i] * HF[i];
    pk.src[i * 4 + 1] = d_in[3 + i * 4 + 1]; pk.off[i * 4 + 1] = off; aloff[i] = off; off += HF[i];
    pk.src[i * 4 + 2] = d_in[3 + i * 4 + 2]; pk.off[i * 4 + 2] = off; aroff[i] = off; off += HF[i];
    pk.src[i * 4 + 3] = d_in[3 + i * 4 + 3]; pk.off[i * 4 + 3] = off; boff[i]  = off; off += HF[i];
  }
  pk.off[20] = off;
  int totalSmall = off;

  k_detect<<<1, 64, 0, stream>>>((const unsigned short*)d_in[0], flag);
  hipMemsetAsync(fill, 0, (size_t)NN * 4, stream);
  { int n = NN * 128; k_cvt_x<<<(n + 255) / 256, 256, 0, stream>>>(d_in[0], xh, n, flag); }
  k_cvt_small<<<(totalSmall + 255) / 256, 256, 0, stream>>>(pk, smallf, totalSmall, flag);
  { dim3 g(128, 5); k_prep_w<<<g, 256, 0, stream>>>(wpk, wt, flag); }
  k_count<<<(NE + 255) / 256, 256, 0, stream>>>(dstIdx, fill);
  int nch = (NN + 255) / 256;
  k_scan1<<<nch, 256, 0, stream>>>(fill, indptr, csum);
  k_scan2<<<1, 256, 0, stream>>>(csum, nch);
  k_scan3<<<nch, 256, 0, stream>>>(indptr, csum, fill);
  k_fill<<<(NE + 255) / 256, 256, 0, stream>>>(srcIdx, dstIdx, fill, csr);

  const int nwaveblk = (NN * 64 + 255) / 256;

  const unsigned short* hin = xh;
  unsigned short* hout = hb0;
  for (int L = 0; L < 4; L++) {
    int K = fin[L], Nc = HF[L], H = Hh[L];
    const float* alp = smallf + aloff[L];
    const float* arp = smallf + aroff[L];
    const float* bp  = smallf + boff[L];
    dim3 gg(Nc / 64, (NN + 63) / 64);
    const void* araw = (L == 0) ? d_in[0] : (const void*)hin;
    k_gemm_mfma<<<gg, 256, 0, stream>>>(araw, hin, wt + WtOff[L], zh, alp, arp, el, er,
                                        NN, K, Nc, H, flag);
    if (L == 0)      k_agg_f<256, 4><<<nwaveblk, 256, 0, stream>>>(indptr, csr, el, er, zh, bp, hout);
    else if (L == 3) k_agg_f<64, 1><<<nwaveblk, 256, 0, stream>>>(indptr, csr, el, er, zh, bp, hout);
    else             k_agg_f<128, 2><<<nwaveblk, 256, 0, stream>>>(indptr, csr, el, er, zh, bp, hout);
    hin = hout;
    hout = (hout == hb0) ? hb1 : hb0;
  }
  // layer 5
  k_l5<<<(NN + 255) / 256, 256, 0, stream>>>(hin, smallf + w5off, smallf + aloff[4],
                                             smallf + aroff[4], z5, el, er);
  k_agg4_f<<<(NN + 255) / 256, 256, 0, stream>>>(indptr, csr, el, er, z5, smallf + boff[4], d_out, flag);
}